// Round 3
// baseline (302.466 us; speedup 1.0000x reference)
//
#include <hip/hip_runtime.h>

#define NBOND 96
#define HBS 158
#define NSTEP 288
#define NT 320

__global__ __launch_bounds__(NT, 1)
void gcn_mp_kernel(const int* __restrict__ a2b,
                   const int* __restrict__ b2a,
                   const int* __restrict__ b2revb,
                   const float* __restrict__ f_bonds,
                   const float* __restrict__ bond_sum,
                   const float* __restrict__ W0,
                   const float* __restrict__ b0,
                   const float* __restrict__ W1, const float* __restrict__ b1,
                   const float* __restrict__ W2, const float* __restrict__ b2v,
                   const float* __restrict__ W3, const float* __restrict__ b3,
                   const float* __restrict__ W4, const float* __restrict__ b4,
                   float* __restrict__ out)
{
  const int m  = blockIdx.x;
  const int t  = threadIdx.x;
  const int og = t >> 3;       // 0..39  -> outputs og*4 .. og*4+3
  const int s  = t & 7;        // 0..7   -> k-slice [s*40, s*40+40)

  __shared__ __align__(16) float fb[NBOND * 160];   // rows padded to 160, pad cols = 0
  __shared__ __align__(16) float xv[2][320];        // double-buffered x = [fb[c] | bs]
  __shared__ int sDp[NSTEP];                        // d-1 | (alias_with_prev_c << 16)
  __shared__ int sRp[NSTEP];                        // rev | (alias_with_prev_c << 16)
  __shared__ __align__(16) float mpb[160];
  __shared__ float hb1[112], hb2[72], hb3[40];

  // ---- stage fb (pad cols >= 158 zeroed)
  for (int idx = t; idx < NBOND * 160; idx += NT) {
    int r = idx / 160, o = idx - r * 160;
    fb[idx] = (o < HBS) ? f_bonds[(m * NBOND + r) * HBS + o] : 0.f;
  }
  // ---- index + alias-flag precompute (addresses data-independent)
  if (t < NSTEP) {
    int i = t, c = i / 3, j = i - 3 * c;
    int a  = b2a[m * NBOND + c];
    int d  = a2b[(m * NBOND + a) * 3 + j] - 1;   // 0..95
    int rv = b2revb[m * NBOND + c];              // 0..95
    int cp = (i == 0) ? -1 : (i - 1) / 3;        // row written by previous step
    sDp[i] = d  | ((d  == cp) ? 0x10000 : 0);
    sRp[i] = rv | ((rv == cp) ? 0x10000 : 0);
  }

  // ---- W0 fragment in registers: thread (og,s) holds rows og*4..+3, k in [s*40, s*40+40)
  float w[4][40];
  float b0r[4];
#pragma unroll
  for (int r = 0; r < 4; ++r) {
    const int o = og * 4 + r;
    b0r[r] = (o < HBS) ? b0[o] : 0.f;
#pragma unroll
    for (int kk = 0; kk < 40; ++kk) {
      const int k = s * 40 + kk;                 // padded K=320
      const int col = (k < 160) ? k : (k - 2);   // [160,318) -> 158 + (k-160)
      const bool valid = (o < HBS) && ((k < 160) ? (k < HBS) : (k < 160 + HBS));
      w[r][kk] = valid ? W0[o * (2 * HBS) + col] : 0.f;
    }
  }
  __syncthreads();

  // ---- build x for step 0 (all-original fb state)
  if (t < 160) {
    int d0 = sDp[0] & 0xFFFF, r0 = sRp[0] & 0xFFFF;
    xv[0][t] = fb[t];                            // row c=0 original (pads 0)
    float bsv = ((t < HBS) ? bond_sum[m * HBS + t] : 0.f)
              + fb[d0 * 160 + t] - fb[r0 * 160 + t];
    xv[0][160 + t] = bsv;                        // pads stay 0
  }
  __syncthreads();

  float cs0 = 0.f, cs1 = 0.f, cs2 = 0.f, cs3 = 0.f;
  int p = 0;

#pragma unroll 1
  for (int i = 0; i < NSTEP; ++i) {
    const int c  = i / 3;
    const int j  = i - 3 * c;
    const int i1 = i + 1;
    const int c1 = i1 / 3;
    const int j1 = i1 - 3 * c1;
    const bool hn = (i1 < NSTEP);

    // ---- early loads: current x slice (broadcast within s-groups)
    const float4* xp = (const float4*)(&xv[p][s * 40]);
    float4 x0 = xp[0], x1 = xp[1], x2 = xp[2], x3 = xp[3], x4 = xp[4];
    float4 x5 = xp[5], x6 = xp[6], x7 = xp[7], x8 = xp[8], x9 = xp[9];

    // ---- early loads for next-step x prep
    float4 nxr = make_float4(0.f, 0.f, 0.f, 0.f);
    float2 dd = make_float2(0.f, 0.f), rr = make_float2(0.f, 0.f), bo = make_float2(0.f, 0.f);
    int aD = 0, aR = 0, e0 = 0;
    if (hn) {
      if (s == 1 && j1 == 0) {
        // row c1 is pristine until its own steps -> race-free pre-barrier read
        nxr = *(const float4*)(&fb[c1 * 160 + og * 4]);
      }
      if (s >= 2 && s <= 3) {
        const int pd = sDp[i1], pr = sRp[i1];
        const int d  = pd & 0xFFFF;  aD = pd >> 16;
        const int rv = pr & 0xFFFF;  aR = pr >> 16;
        e0 = og * 4 + (s - 2) * 2;                 // 2 bs elements per thread
        dd = *(const float2*)(&fb[d  * 160 + e0]); // stale-if-alias: fixed by select below
        rr = *(const float2*)(&fb[rv * 160 + e0]);
        bo = *(const float2*)(&xv[p][160 + e0]);   // old bs
      }
    }

    // ---- 160 FMAs: 4 outputs x 40-k slice, fully static indexing
    float a0 = 0.f, a1 = 0.f, a2 = 0.f, a3 = 0.f;
#define QSTEP(qq, xx) \
    a0 = fmaf(w[0][4*qq+0], xx.x, a0); a1 = fmaf(w[1][4*qq+0], xx.x, a1); \
    a2 = fmaf(w[2][4*qq+0], xx.x, a2); a3 = fmaf(w[3][4*qq+0], xx.x, a3); \
    a0 = fmaf(w[0][4*qq+1], xx.y, a0); a1 = fmaf(w[1][4*qq+1], xx.y, a1); \
    a2 = fmaf(w[2][4*qq+1], xx.y, a2); a3 = fmaf(w[3][4*qq+1], xx.y, a3); \
    a0 = fmaf(w[0][4*qq+2], xx.z, a0); a1 = fmaf(w[1][4*qq+2], xx.z, a1); \
    a2 = fmaf(w[2][4*qq+2], xx.z, a2); a3 = fmaf(w[3][4*qq+2], xx.z, a3); \
    a0 = fmaf(w[0][4*qq+3], xx.w, a0); a1 = fmaf(w[1][4*qq+3], xx.w, a1); \
    a2 = fmaf(w[2][4*qq+3], xx.w, a2); a3 = fmaf(w[3][4*qq+3], xx.w, a3);
    QSTEP(0, x0) QSTEP(1, x1) QSTEP(2, x2) QSTEP(3, x3) QSTEP(4, x4)
    QSTEP(5, x5) QSTEP(6, x6) QSTEP(7, x7) QSTEP(8, x8) QSTEP(9, x9)
#undef QSTEP

    // ---- butterfly reduce over the 8 k-slices: all lanes end with full nf
    a0 += __shfl_xor(a0, 1); a0 += __shfl_xor(a0, 2); a0 += __shfl_xor(a0, 4);
    a1 += __shfl_xor(a1, 1); a1 += __shfl_xor(a1, 2); a1 += __shfl_xor(a1, 4);
    a2 += __shfl_xor(a2, 1); a2 += __shfl_xor(a2, 2); a2 += __shfl_xor(a2, 4);
    a3 += __shfl_xor(a3, 1); a3 += __shfl_xor(a3, 2); a3 += __shfl_xor(a3, 4);
    a0 += b0r[0]; a1 += b0r[1]; a2 += b0r[2]; a3 += b0r[3];

    // ---- writes (roles by s); one barrier covers everything
    if (s == 0) {
      *(float4*)(&fb[c * 160 + og * 4]) = make_float4(a0, a1, a2, a3);
    }
    if (hn) {
      if (s == 1) {
        float4 wv = (j1 == 0) ? nxr : make_float4(a0, a1, a2, a3);
        *(float4*)(&xv[p ^ 1][og * 4]) = wv;       // next x, first half
      }
      if (s >= 2 && s <= 3) {
        float sA = (s == 2) ? a0 : a2;             // nf at elements e0, e0+1
        float sB = (s == 2) ? a1 : a3;
        float vd0 = aD ? sA : dd.x;
        float vd1 = aD ? sB : dd.y;
        float vr0 = aR ? sA : rr.x;
        float vr1 = aR ? sB : rr.y;
        *(float2*)(&xv[p ^ 1][160 + e0]) =
            make_float2(bo.x + vd0 - vr0, bo.y + vd1 - vr1);   // next bs
      }
    }
    if (j == 2) { cs0 += a0; cs1 += a1; cs2 += a2; cs3 += a3; }

    p ^= 1;
    __syncthreads();
  }

  // ---- mp = column sums (accumulated in registers at j==2 steps)
  if (s == 0) {
    *(float4*)(&mpb[og * 4]) = make_float4(cs0, cs1, cs2, cs3);  // pads (158,159) are 0
  }
  __syncthreads();

  // ---- tiny MLP: 158 -> 110 (no relu) -> 70 (relu) -> 35 (relu) -> 1
  if (t < 110) {
    float acc = b1[t];
    for (int k = 0; k < HBS; ++k) acc = fmaf(mpb[k], W1[t * HBS + k], acc);
    hb1[t] = acc;
  }
  __syncthreads();
  if (t < 70) {
    float acc = b2v[t];
    for (int k = 0; k < 110; ++k) acc = fmaf(hb1[k], W2[t * 110 + k], acc);
    hb2[t] = fmaxf(acc, 0.f);
  }
  __syncthreads();
  if (t < 35) {
    float acc = b3[t];
    for (int k = 0; k < 70; ++k) acc = fmaf(hb2[k], W3[t * 70 + k], acc);
    hb3[t] = fmaxf(acc, 0.f);
  }
  __syncthreads();
  if (t == 0) {
    float acc = b4[0];
    for (int k = 0; k < 35; ++k) acc = fmaf(hb3[k], W4[k], acc);
    out[m] = acc;
  }
}

extern "C" void kernel_launch(void* const* d_in, const int* in_sizes, int n_in,
                              void* d_out, int out_size, void* d_ws, size_t ws_size,
                              hipStream_t stream)
{
  const int*   a2b      = (const int*)d_in[0];
  const int*   b2a      = (const int*)d_in[1];
  const int*   b2revb   = (const int*)d_in[2];
  const float* f_bonds  = (const float*)d_in[3];
  /* d_in[4] = f_atoms_ (unused by forward) */
  const float* bond_sum = (const float*)d_in[5];
  const float* W0 = (const float*)d_in[6];
  const float* b0 = (const float*)d_in[7];
  const float* W1 = (const float*)d_in[8];
  const float* b1 = (const float*)d_in[9];
  const float* W2 = (const float*)d_in[10];
  const float* b2 = (const float*)d_in[11];
  const float* W3 = (const float*)d_in[12];
  const float* b3 = (const float*)d_in[13];
  const float* W4 = (const float*)d_in[14];
  const float* b4 = (const float*)d_in[15];

  gcn_mp_kernel<<<dim3(96), dim3(NT), 0, stream>>>(
      a2b, b2a, b2revb, f_bonds, bond_sum,
      W0, b0, W1, b1, W2, b2, W3, b3, W4, b4,
      (float*)d_out);
}

// Round 4
// 292.945 us; speedup vs baseline: 1.0325x; 1.0325x over previous
//
#include <hip/hip_runtime.h>

#define NBOND 96
#define HBS 158
#define NSTEP 288
#define NT 320

typedef float f4 __attribute__((ext_vector_type(4)));
#define Z4 ((f4){0.f, 0.f, 0.f, 0.f})
#define MK4(P, B) ((f4){(P)[(B)], (P)[(B)+1], (P)[(B)+2], (P)[(B)+3]})

__global__ __launch_bounds__(NT, 1)
void gcn_mp_kernel(const int* __restrict__ a2b,
                   const int* __restrict__ b2a,
                   const int* __restrict__ b2revb,
                   const float* __restrict__ f_bonds,
                   const float* __restrict__ bond_sum,
                   const float* __restrict__ W0,
                   const float* __restrict__ b0,
                   const float* __restrict__ W1, const float* __restrict__ b1,
                   const float* __restrict__ W2, const float* __restrict__ b2v,
                   const float* __restrict__ W3, const float* __restrict__ b3,
                   const float* __restrict__ W4, const float* __restrict__ b4,
                   float* __restrict__ out)
{
  const int m  = blockIdx.x;
  const int t  = threadIdx.x;
  const int og = t >> 3;       // 0..39  -> outputs og*4 .. og*4+3
  const int s  = t & 7;        // 0..7   -> k-slice [s*40, s*40+40)

  __shared__ __align__(16) float fb[NBOND * 160];   // rows padded to 160, pad cols = 0
  __shared__ __align__(16) float xv[2][320];        // double-buffered x = [fb[c] | bs]
  __shared__ int sDp[NSTEP];                        // d-1 | (alias_with_prev_c << 16)
  __shared__ int sRp[NSTEP];                        // rev | (alias_with_prev_c << 16)
  __shared__ __align__(16) float mpb[160];
  __shared__ float hb1[112], hb2[72], hb3[40];

  // ---- stage fb (pad cols >= 158 zeroed)
  for (int idx = t; idx < NBOND * 160; idx += NT) {
    int r = idx / 160, o = idx - r * 160;
    fb[idx] = (o < HBS) ? f_bonds[(m * NBOND + r) * HBS + o] : 0.f;
  }
  // ---- index + alias-flag precompute (addresses data-independent)
  if (t < NSTEP) {
    int i = t, c = i / 3, j = i - 3 * c;
    int a  = b2a[m * NBOND + c];
    int d  = a2b[(m * NBOND + a) * 3 + j] - 1;   // 0..95
    int rv = b2revb[m * NBOND + c];              // 0..95
    int cp = (i == 0) ? -1 : (i - 1) / 3;        // row written by previous step
    sDp[i] = d  | ((d  == cp) ? 0x10000 : 0);
    sRp[i] = rv | ((rv == cp) ? 0x10000 : 0);
  }

  // ---- W0 in NAMED vector registers: thread (og,s) holds rows og*4..+3, k in [s*40,s*40+40)
  // padded-K col base: k<160 -> col k ; k>=160 -> col k-2
  const int o0 = og * 4;
  const int cb = (s < 4) ? s * 40 : s * 40 - 2;
  const bool edge = (s == 3) || (s == 7);          // last 2 k's of the slice invalid
  const float* P0 = W0 + o0 * (2 * HBS) + cb;
  const float* P1 = W0 + (o0 + 1) * (2 * HBS) + cb;
  const float* P2 = W0 + ((o0 + 2 < HBS) ? o0 + 2 : HBS - 1) * (2 * HBS) + cb;
  const float* P3 = W0 + ((o0 + 3 < HBS) ? o0 + 3 : HBS - 1) * (2 * HBS) + cb;

#define DECLROW(R, P) \
  f4 w##R##0 = MK4(P, 0),  w##R##1 = MK4(P, 4),  w##R##2 = MK4(P, 8),  \
     w##R##3 = MK4(P, 12), w##R##4 = MK4(P, 16), w##R##5 = MK4(P, 20), \
     w##R##6 = MK4(P, 24), w##R##7 = MK4(P, 28), w##R##8 = MK4(P, 32); \
  f4 w##R##9 = (f4){(P)[36], (P)[37], edge ? 0.f : (P)[38], edge ? 0.f : (P)[39]};
  DECLROW(0, P0)
  DECLROW(1, P1)
  DECLROW(2, P2)
  DECLROW(3, P3)
#undef DECLROW
  if (o0 + 2 >= HBS) {   // og==39: rows 158,159 are padding
    w20 = Z4; w21 = Z4; w22 = Z4; w23 = Z4; w24 = Z4;
    w25 = Z4; w26 = Z4; w27 = Z4; w28 = Z4; w29 = Z4;
    w30 = Z4; w31 = Z4; w32 = Z4; w33 = Z4; w34 = Z4;
    w35 = Z4; w36 = Z4; w37 = Z4; w38 = Z4; w39 = Z4;
  }
  const float b0r0 = b0[o0];
  const float b0r1 = b0[o0 + 1];
  const float b0r2 = (o0 + 2 < HBS) ? b0[o0 + 2] : 0.f;
  const float b0r3 = (o0 + 3 < HBS) ? b0[o0 + 3] : 0.f;

  __syncthreads();

  // ---- build x for step 0 (all-original fb state)
  if (t < 160) {
    int d0 = sDp[0] & 0xFFFF, r0 = sRp[0] & 0xFFFF;
    xv[0][t] = fb[t];
    float bsv = ((t < HBS) ? bond_sum[m * HBS + t] : 0.f)
              + fb[d0 * 160 + t] - fb[r0 * 160 + t];
    xv[0][160 + t] = bsv;
  }
  __syncthreads();

  float cs0 = 0.f, cs1 = 0.f, cs2 = 0.f, cs3 = 0.f;
  int p = 0;

#pragma unroll 1
  for (int i = 0; i < NSTEP; ++i) {
    const int c  = i / 3;
    const int j  = i - 3 * c;
    const int i1 = i + 1;
    const int c1 = i1 / 3;
    const int j1 = i1 - 3 * c1;
    const bool hn = (i1 < NSTEP);

    const f4* XP = (const f4*)(&xv[p][s * 40]);
    f4 xa = XP[0], xb = XP[1], xc = XP[2], xd = XP[3];

    // ---- early loads for next-step x prep
    f4 nxr = Z4;
    float2 dd = make_float2(0.f, 0.f), rr = make_float2(0.f, 0.f), bo = make_float2(0.f, 0.f);
    int aD = 0, aR = 0, e0 = 0;
    if (hn) {
      if (s == 1 && j1 == 0) {
        const float* q = &fb[c1 * 160 + og * 4];   // pristine row: race-free pre-barrier
        nxr = (f4){q[0], q[1], q[2], q[3]};
      }
      if (s >= 2 && s <= 3) {
        const int pd = sDp[i1], pr = sRp[i1];
        const int d  = pd & 0xFFFF;  aD = pd >> 16;
        const int rv = pr & 0xFFFF;  aR = pr >> 16;
        e0 = og * 4 + (s - 2) * 2;
        dd = *(const float2*)(&fb[d  * 160 + e0]); // stale-if-alias: select below
        rr = *(const float2*)(&fb[rv * 160 + e0]);
        bo = *(const float2*)(&xv[p][160 + e0]);
      }
    }

    // ---- 160 FMAs, fully static indexing on named vector regs
    float a0 = 0.f, a1 = 0.f, a2 = 0.f, a3 = 0.f;
#define QSTEP(Q, XX) \
    a0 = fmaf(w0##Q[0], XX[0], a0); a1 = fmaf(w1##Q[0], XX[0], a1); \
    a2 = fmaf(w2##Q[0], XX[0], a2); a3 = fmaf(w3##Q[0], XX[0], a3); \
    a0 = fmaf(w0##Q[1], XX[1], a0); a1 = fmaf(w1##Q[1], XX[1], a1); \
    a2 = fmaf(w2##Q[1], XX[1], a2); a3 = fmaf(w3##Q[1], XX[1], a3); \
    a0 = fmaf(w0##Q[2], XX[2], a0); a1 = fmaf(w1##Q[2], XX[2], a1); \
    a2 = fmaf(w2##Q[2], XX[2], a2); a3 = fmaf(w3##Q[2], XX[2], a3); \
    a0 = fmaf(w0##Q[3], XX[3], a0); a1 = fmaf(w1##Q[3], XX[3], a1); \
    a2 = fmaf(w2##Q[3], XX[3], a2); a3 = fmaf(w3##Q[3], XX[3], a3);
    QSTEP(0, xa) xa = XP[4];
    QSTEP(1, xb) xb = XP[5];
    QSTEP(2, xc) xc = XP[6];
    QSTEP(3, xd) xd = XP[7];
    QSTEP(4, xa) xa = XP[8];
    QSTEP(5, xb) xb = XP[9];
    QSTEP(6, xc)
    QSTEP(7, xd)
    QSTEP(8, xa)
    QSTEP(9, xb)
#undef QSTEP

    // ---- butterfly reduce over the 8 k-slices: every lane ends with full nf
    a0 += __shfl_xor(a0, 1); a0 += __shfl_xor(a0, 2); a0 += __shfl_xor(a0, 4);
    a1 += __shfl_xor(a1, 1); a1 += __shfl_xor(a1, 2); a1 += __shfl_xor(a1, 4);
    a2 += __shfl_xor(a2, 1); a2 += __shfl_xor(a2, 2); a2 += __shfl_xor(a2, 4);
    a3 += __shfl_xor(a3, 1); a3 += __shfl_xor(a3, 2); a3 += __shfl_xor(a3, 4);
    a0 += b0r0; a1 += b0r1; a2 += b0r2; a3 += b0r3;

    // ---- writes (roles by s); single barrier covers everything
    if (s == 0) {
      *(float4*)(&fb[c * 160 + og * 4]) = make_float4(a0, a1, a2, a3);
    }
    if (hn) {
      if (s == 1) {
        float4 wv = (j1 == 0) ? make_float4(nxr[0], nxr[1], nxr[2], nxr[3])
                              : make_float4(a0, a1, a2, a3);
        *(float4*)(&xv[p ^ 1][og * 4]) = wv;       // next x, first half
      }
      if (s >= 2 && s <= 3) {
        float sA = (s == 2) ? a0 : a2;             // nf at elements e0, e0+1
        float sB = (s == 2) ? a1 : a3;
        float vd0 = aD ? sA : dd.x;
        float vd1 = aD ? sB : dd.y;
        float vr0 = aR ? sA : rr.x;
        float vr1 = aR ? sB : rr.y;
        *(float2*)(&xv[p ^ 1][160 + e0]) =
            make_float2(bo.x + vd0 - vr0, bo.y + vd1 - vr1);   // next bs
      }
    }
    if (j == 2) { cs0 += a0; cs1 += a1; cs2 += a2; cs3 += a3; }

    p ^= 1;
    __syncthreads();
  }

  // ---- mp = column sums (accumulated in registers at j==2 steps)
  if (s == 0) {
    *(float4*)(&mpb[og * 4]) = make_float4(cs0, cs1, cs2, cs3);  // pads (158,159) are 0
  }
  __syncthreads();

  // ---- tiny MLP: 158 -> 110 (no relu) -> 70 (relu) -> 35 (relu) -> 1
  if (t < 110) {
    float acc = b1[t];
    for (int k = 0; k < HBS; ++k) acc = fmaf(mpb[k], W1[t * HBS + k], acc);
    hb1[t] = acc;
  }
  __syncthreads();
  if (t < 70) {
    float acc = b2v[t];
    for (int k = 0; k < 110; ++k) acc = fmaf(hb1[k], W2[t * 110 + k], acc);
    hb2[t] = fmaxf(acc, 0.f);
  }
  __syncthreads();
  if (t < 35) {
    float acc = b3[t];
    for (int k = 0; k < 70; ++k) acc = fmaf(hb2[k], W3[t * 70 + k], acc);
    hb3[t] = fmaxf(acc, 0.f);
  }
  __syncthreads();
  if (t == 0) {
    float acc = b4[0];
    for (int k = 0; k < 35; ++k) acc = fmaf(hb3[k], W4[k], acc);
    out[m] = acc;
  }
}

extern "C" void kernel_launch(void* const* d_in, const int* in_sizes, int n_in,
                              void* d_out, int out_size, void* d_ws, size_t ws_size,
                              hipStream_t stream)
{
  const int*   a2b      = (const int*)d_in[0];
  const int*   b2a      = (const int*)d_in[1];
  const int*   b2revb   = (const int*)d_in[2];
  const float* f_bonds  = (const float*)d_in[3];
  /* d_in[4] = f_atoms_ (unused by forward) */
  const float* bond_sum = (const float*)d_in[5];
  const float* W0 = (const float*)d_in[6];
  const float* b0 = (const float*)d_in[7];
  const float* W1 = (const float*)d_in[8];
  const float* b1 = (const float*)d_in[9];
  const float* W2 = (const float*)d_in[10];
  const float* b2 = (const float*)d_in[11];
  const float* W3 = (const float*)d_in[12];
  const float* b3 = (const float*)d_in[13];
  const float* W4 = (const float*)d_in[14];
  const float* b4 = (const float*)d_in[15];

  gcn_mp_kernel<<<dim3(96), dim3(NT), 0, stream>>>(
      a2b, b2a, b2revb, f_bonds, bond_sum,
      W0, b0, W1, b1, W2, b2, W3, b3, W4, b4,
      (float*)d_out);
}

// Round 5
// 290.164 us; speedup vs baseline: 1.0424x; 1.0096x over previous
//
#include <hip/hip_runtime.h>

#define NBOND 96
#define HBS 158
#define NSTEP 288
#define NT 320

typedef float f4 __attribute__((ext_vector_type(4)));
#define Z4 ((f4){0.f, 0.f, 0.f, 0.f})
#define MK4(P, B) ((f4){(P)[(B)], (P)[(B)+1], (P)[(B)+2], (P)[(B)+3]})

__global__ __launch_bounds__(NT, 1)
void gcn_mp_kernel(const int* __restrict__ a2b,
                   const int* __restrict__ b2a,
                   const int* __restrict__ b2revb,
                   const float* __restrict__ f_bonds,
                   const float* __restrict__ bond_sum,
                   const float* __restrict__ W0,
                   const float* __restrict__ b0,
                   const float* __restrict__ W1, const float* __restrict__ b1,
                   const float* __restrict__ W2, const float* __restrict__ b2v,
                   const float* __restrict__ W3, const float* __restrict__ b3,
                   const float* __restrict__ W4, const float* __restrict__ b4,
                   float* __restrict__ out)
{
  const int m  = blockIdx.x;
  const int t  = threadIdx.x;
  const int og = t >> 3;       // 0..39  -> outputs og*4 .. og*4+3
  const int s  = t & 7;        // 0..7   -> k-slice [s*40, s*40+40)

  __shared__ __align__(16) float fb[NBOND * 160];   // rows padded to 160, pad cols = 0
  __shared__ __align__(16) float xv[2][320];        // double-buffered x = [fb[c] | bs]
  __shared__ int sDp[NSTEP];                        // d-1 | (alias_with_prev_c << 16)
  __shared__ int sRp[NSTEP];                        // rev | (alias_with_prev_c << 16)
  __shared__ __align__(16) float mpb[160];
  __shared__ float hb1[112], hb2[72], hb3[40];

  // ---- stage fb (pad cols >= 158 zeroed)
  for (int idx = t; idx < NBOND * 160; idx += NT) {
    int r = idx / 160, o = idx - r * 160;
    fb[idx] = (o < HBS) ? f_bonds[(m * NBOND + r) * HBS + o] : 0.f;
  }
  // ---- index + alias-flag precompute (addresses data-independent)
  if (t < NSTEP) {
    int i = t, c = i / 3, j = i - 3 * c;
    int a  = b2a[m * NBOND + c];
    int d  = a2b[(m * NBOND + a) * 3 + j] - 1;   // 0..95
    int rv = b2revb[m * NBOND + c];              // 0..95
    int cp = (i == 0) ? -1 : (i - 1) / 3;        // row written by previous step
    sDp[i] = d  | ((d  == cp) ? 0x10000 : 0);
    sRp[i] = rv | ((rv == cp) ? 0x10000 : 0);
  }

  // ---- W0 in named vector registers: thread (og,s) holds rows og*4..+3, k in [s*40,s*40+40)
  // padded-K col base: k<160 -> col k ; k>=160 -> col k-2
  const int o0 = og * 4;
  const int cb = (s < 4) ? s * 40 : s * 40 - 2;
  const bool edge = (s == 3) || (s == 7);          // last 2 k's of the slice invalid
  const float* P0 = W0 + o0 * (2 * HBS) + cb;
  const float* P1 = W0 + (o0 + 1) * (2 * HBS) + cb;
  const float* P2 = W0 + ((o0 + 2 < HBS) ? o0 + 2 : HBS - 1) * (2 * HBS) + cb;
  const float* P3 = W0 + ((o0 + 3 < HBS) ? o0 + 3 : HBS - 1) * (2 * HBS) + cb;

#define DECLROW(R, P) \
  f4 w##R##0 = MK4(P, 0),  w##R##1 = MK4(P, 4),  w##R##2 = MK4(P, 8),  \
     w##R##3 = MK4(P, 12), w##R##4 = MK4(P, 16), w##R##5 = MK4(P, 20), \
     w##R##6 = MK4(P, 24), w##R##7 = MK4(P, 28), w##R##8 = MK4(P, 32); \
  f4 w##R##9 = (f4){(P)[36], (P)[37], edge ? 0.f : (P)[38], edge ? 0.f : (P)[39]};
  DECLROW(0, P0)
  DECLROW(1, P1)
  DECLROW(2, P2)
  DECLROW(3, P3)
#undef DECLROW
  if (o0 + 2 >= HBS) {   // og==39: rows 158,159 are padding
    w20 = Z4; w21 = Z4; w22 = Z4; w23 = Z4; w24 = Z4;
    w25 = Z4; w26 = Z4; w27 = Z4; w28 = Z4; w29 = Z4;
    w30 = Z4; w31 = Z4; w32 = Z4; w33 = Z4; w34 = Z4;
    w35 = Z4; w36 = Z4; w37 = Z4; w38 = Z4; w39 = Z4;
  }
  const float b0r0 = b0[o0];
  const float b0r1 = b0[o0 + 1];
  const float b0r2 = (o0 + 2 < HBS) ? b0[o0 + 2] : 0.f;
  const float b0r3 = (o0 + 3 < HBS) ? b0[o0 + 3] : 0.f;

  // ---- PIN the weights: opaque asm defs cannot be rematerialized or sunk
  // into the loop, so the allocator must keep them live in VGPRs.
  asm volatile("" : "+v"(w00), "+v"(w01), "+v"(w02), "+v"(w03), "+v"(w04),
                    "+v"(w05), "+v"(w06), "+v"(w07), "+v"(w08), "+v"(w09));
  asm volatile("" : "+v"(w10), "+v"(w11), "+v"(w12), "+v"(w13), "+v"(w14),
                    "+v"(w15), "+v"(w16), "+v"(w17), "+v"(w18), "+v"(w19));
  asm volatile("" : "+v"(w20), "+v"(w21), "+v"(w22), "+v"(w23), "+v"(w24),
                    "+v"(w25), "+v"(w26), "+v"(w27), "+v"(w28), "+v"(w29));
  asm volatile("" : "+v"(w30), "+v"(w31), "+v"(w32), "+v"(w33), "+v"(w34),
                    "+v"(w35), "+v"(w36), "+v"(w37), "+v"(w38), "+v"(w39));

  __syncthreads();

  // ---- build x for step 0 (all-original fb state)
  if (t < 160) {
    int d0 = sDp[0] & 0xFFFF, r0 = sRp[0] & 0xFFFF;
    xv[0][t] = fb[t];
    float bsv = ((t < HBS) ? bond_sum[m * HBS + t] : 0.f)
              + fb[d0 * 160 + t] - fb[r0 * 160 + t];
    xv[0][160 + t] = bsv;
  }
  __syncthreads();

  float cs0 = 0.f, cs1 = 0.f, cs2 = 0.f, cs3 = 0.f;
  int p = 0;

#pragma unroll 1
  for (int i = 0; i < NSTEP; ++i) {
    const int c  = i / 3;
    const int j  = i - 3 * c;
    const int i1 = i + 1;
    const int c1 = i1 / 3;
    const int j1 = i1 - 3 * c1;
    const bool hn = (i1 < NSTEP);

    const f4* XP = (const f4*)(&xv[p][s * 40]);
    f4 xa = XP[0], xb = XP[1], xc = XP[2], xd = XP[3];

    // ---- early loads for next-step x prep
    f4 nxr = Z4;
    float2 dd = make_float2(0.f, 0.f), rr = make_float2(0.f, 0.f), bo = make_float2(0.f, 0.f);
    int aD = 0, aR = 0, e0 = 0;
    if (hn) {
      if (s == 1 && j1 == 0) {
        const float* q = &fb[c1 * 160 + og * 4];   // pristine row: race-free pre-barrier
        nxr = (f4){q[0], q[1], q[2], q[3]};
      }
      if (s >= 2 && s <= 3) {
        const int pd = sDp[i1], pr = sRp[i1];
        const int d  = pd & 0xFFFF;  aD = pd >> 16;
        const int rv = pr & 0xFFFF;  aR = pr >> 16;
        e0 = og * 4 + (s - 2) * 2;
        dd = *(const float2*)(&fb[d  * 160 + e0]); // stale-if-alias: select below
        rr = *(const float2*)(&fb[rv * 160 + e0]);
        bo = *(const float2*)(&xv[p][160 + e0]);
      }
    }

    // ---- 160 FMAs, fully static indexing on pinned vector regs
    float a0 = 0.f, a1 = 0.f, a2 = 0.f, a3 = 0.f;
#define QSTEP(Q, XX) \
    a0 = fmaf(w0##Q[0], XX[0], a0); a1 = fmaf(w1##Q[0], XX[0], a1); \
    a2 = fmaf(w2##Q[0], XX[0], a2); a3 = fmaf(w3##Q[0], XX[0], a3); \
    a0 = fmaf(w0##Q[1], XX[1], a0); a1 = fmaf(w1##Q[1], XX[1], a1); \
    a2 = fmaf(w2##Q[1], XX[1], a2); a3 = fmaf(w3##Q[1], XX[1], a3); \
    a0 = fmaf(w0##Q[2], XX[2], a0); a1 = fmaf(w1##Q[2], XX[2], a1); \
    a2 = fmaf(w2##Q[2], XX[2], a2); a3 = fmaf(w3##Q[2], XX[2], a3); \
    a0 = fmaf(w0##Q[3], XX[3], a0); a1 = fmaf(w1##Q[3], XX[3], a1); \
    a2 = fmaf(w2##Q[3], XX[3], a2); a3 = fmaf(w3##Q[3], XX[3], a3);
    QSTEP(0, xa) xa = XP[4];
    QSTEP(1, xb) xb = XP[5];
    QSTEP(2, xc) xc = XP[6];
    QSTEP(3, xd) xd = XP[7];
    QSTEP(4, xa) xa = XP[8];
    QSTEP(5, xb) xb = XP[9];
    QSTEP(6, xc)
    QSTEP(7, xd)
    QSTEP(8, xa)
    QSTEP(9, xb)
#undef QSTEP

    // ---- butterfly reduce over the 8 k-slices: every lane ends with full nf
    a0 += __shfl_xor(a0, 1); a0 += __shfl_xor(a0, 2); a0 += __shfl_xor(a0, 4);
    a1 += __shfl_xor(a1, 1); a1 += __shfl_xor(a1, 2); a1 += __shfl_xor(a1, 4);
    a2 += __shfl_xor(a2, 1); a2 += __shfl_xor(a2, 2); a2 += __shfl_xor(a2, 4);
    a3 += __shfl_xor(a3, 1); a3 += __shfl_xor(a3, 2); a3 += __shfl_xor(a3, 4);
    a0 += b0r0; a1 += b0r1; a2 += b0r2; a3 += b0r3;

    // ---- writes (roles by s); single barrier covers everything
    if (s == 0) {
      *(float4*)(&fb[c * 160 + og * 4]) = make_float4(a0, a1, a2, a3);
    }
    if (hn) {
      if (s == 1) {
        float4 wv = (j1 == 0) ? make_float4(nxr[0], nxr[1], nxr[2], nxr[3])
                              : make_float4(a0, a1, a2, a3);
        *(float4*)(&xv[p ^ 1][og * 4]) = wv;       // next x, first half
      }
      if (s >= 2 && s <= 3) {
        float sA = (s == 2) ? a0 : a2;             // nf at elements e0, e0+1
        float sB = (s == 2) ? a1 : a3;
        float vd0 = aD ? sA : dd.x;
        float vd1 = aD ? sB : dd.y;
        float vr0 = aR ? sA : rr.x;
        float vr1 = aR ? sB : rr.y;
        *(float2*)(&xv[p ^ 1][160 + e0]) =
            make_float2(bo.x + vd0 - vr0, bo.y + vd1 - vr1);   // next bs
      }
    }
    if (j == 2) { cs0 += a0; cs1 += a1; cs2 += a2; cs3 += a3; }

    p ^= 1;
    __syncthreads();
  }

  // ---- mp = column sums (accumulated in registers at j==2 steps)
  if (s == 0) {
    *(float4*)(&mpb[og * 4]) = make_float4(cs0, cs1, cs2, cs3);  // pads (158,159) are 0
  }
  __syncthreads();

  // ---- tiny MLP: 158 -> 110 (no relu) -> 70 (relu) -> 35 (relu) -> 1
  if (t < 110) {
    float acc = b1[t];
    for (int k = 0; k < HBS; ++k) acc = fmaf(mpb[k], W1[t * HBS + k], acc);
    hb1[t] = acc;
  }
  __syncthreads();
  if (t < 70) {
    float acc = b2v[t];
    for (int k = 0; k < 110; ++k) acc = fmaf(hb1[k], W2[t * 110 + k], acc);
    hb2[t] = fmaxf(acc, 0.f);
  }
  __syncthreads();
  if (t < 35) {
    float acc = b3[t];
    for (int k = 0; k < 70; ++k) acc = fmaf(hb2[k], W3[t * 70 + k], acc);
    hb3[t] = fmaxf(acc, 0.f);
  }
  __syncthreads();
  if (t == 0) {
    float acc = b4[0];
    for (int k = 0; k < 35; ++k) acc = fmaf(hb3[k], W4[k], acc);
    out[m] = acc;
  }
}

extern "C" void kernel_launch(void* const* d_in, const int* in_sizes, int n_in,
                              void* d_out, int out_size, void* d_ws, size_t ws_size,
                              hipStream_t stream)
{
  const int*   a2b      = (const int*)d_in[0];
  const int*   b2a      = (const int*)d_in[1];
  const int*   b2revb   = (const int*)d_in[2];
  const float* f_bonds  = (const float*)d_in[3];
  /* d_in[4] = f_atoms_ (unused by forward) */
  const float* bond_sum = (const float*)d_in[5];
  const float* W0 = (const float*)d_in[6];
  const float* b0 = (const float*)d_in[7];
  const float* W1 = (const float*)d_in[8];
  const float* b1 = (const float*)d_in[9];
  const float* W2 = (const float*)d_in[10];
  const float* b2 = (const float*)d_in[11];
  const float* W3 = (const float*)d_in[12];
  const float* b3 = (const float*)d_in[13];
  const float* W4 = (const float*)d_in[14];
  const float* b4 = (const float*)d_in[15];

  gcn_mp_kernel<<<dim3(96), dim3(NT), 0, stream>>>(
      a2b, b2a, b2revb, f_bonds, bond_sum,
      W0, b0, W1, b1, W2, b2, W3, b3, W4, b4,
      (float*)d_out);
}